// Round 11
// baseline (26.428 us; speedup 1.0000x reference)
//
#include <hip/hip_runtime.h>
#include <cfloat>

#define BB    128
#define CC    4
#define NBOXN 131072
#define SPLIT 16                 // chunk-blocks per row
#define NBLK  (BB * SPLIT)       // 2048 blocks
#define F4_PER_CHUNK 2048        // 8192 elems / 4
#define F4_PER_STRIPE 8          // float4s per thread

typedef float v4f __attribute__((ext_vector_type(4)));

// sorted-insert into descending triple (a>=b>=c), 3 depth-1 ops via med3
__device__ __forceinline__ void ins3(float v, float& a, float& b, float& c) {
    const float na = fmaxf(a, v);
    const float nb = __builtin_amdgcn_fmed3f(a, b, v);
    const float nc = __builtin_amdgcn_fmed3f(b, c, v);
    a = na; b = nb; c = nc;
}

__device__ __forceinline__ float bce(float x, float t) {
    return fmaxf(x, 0.0f) - x * t + log1pf(expf(-fabsf(x)));
}

// agent-scope store: single sc0/sc1 global_store, bypasses L1/L2 (R7-proven)
__device__ __forceinline__ void st_agent(float* p, float v) {
    __hip_atomic_store(p, v, __ATOMIC_RELAXED, __HIP_MEMORY_SCOPE_AGENT);
}

// Single fused kernel: per-chunk exact top-3 -> per-row handoff (16-deep
// counter) -> row loss -> global handoff (128-deep counter) -> scalar out.
__global__ __launch_bounds__(256) void k_fused(
        const float* __restrict__ cp,
        const float* __restrict__ rp,
        const int*   __restrict__ box_idxs,
        const float* __restrict__ rt,
        unsigned*    __restrict__ rowcnt,   // [BB], zeroed per launch
        unsigned*    __restrict__ done,     // [1],  zeroed per launch
        float*       __restrict__ cand,     // [BB*48]
        float*       __restrict__ posval,   // [BB]
        float*       __restrict__ rowreg,   // [BB*CC]
        float*       __restrict__ rowloss,  // [BB]
        float*       __restrict__ out) {
    const int row   = blockIdx.x >> 4;
    const int chunk = blockIdx.x & 15;
    const int tid   = threadIdx.x;
    const int bidx  = box_idxs[row];

    // side jobs hidden under the stream (chunk-0 block of each row);
    // sc1 stores so the row finalizer (any block) can read them.
    if (chunk == 0) {
        if (tid < CC) {
            const float pv = rp[((size_t)row * CC + tid) * NBOXN + bidx];
            const float d  = fabsf(pv - rt[row * CC + tid]);
            st_agent(&rowreg[row * CC + tid], (d < 1.0f) ? 0.5f * d * d : (d - 0.5f));
        } else if (tid == CC) {
            st_agent(&posval[row], cp[(size_t)row * NBOXN + bidx]);
        }
    }

    const v4f* src = reinterpret_cast<const v4f*>(cp + (size_t)row * NBOXN)
                     + chunk * F4_PER_CHUNK;
    const int gbase = (chunk * F4_PER_CHUNK) << 2;

    // per-thread exact top-3; nontemporal read-once stream
    float a = -FLT_MAX, b = -FLT_MAX, c = -FLT_MAX;
    #pragma unroll
    for (int k = 0; k < F4_PER_STRIPE; ++k) {
        const int j = tid + (k << 8);
        v4f v = __builtin_nontemporal_load(&src[j]);
        const int g = gbase + (j << 2);
        if ((unsigned)(bidx - g) < 4u) {     // rare, exec-mask-skipped
            if      (bidx == g)     v.x = -FLT_MAX;
            else if (bidx == g + 1) v.y = -FLT_MAX;
            else if (bidx == g + 2) v.z = -FLT_MAX;
            else                    v.w = -FLT_MAX;
        }
        ins3(v.x, a, b, c); ins3(v.y, a, b, c);
        ins3(v.z, a, b, c); ins3(v.w, a, b, c);
    }

    // wave64 shuffle tree + 4-wave LDS merge
    for (int off = 32; off >= 1; off >>= 1) {
        const float a2 = __shfl_down(a, off);
        const float b2 = __shfl_down(b, off);
        const float c2 = __shfl_down(c, off);
        ins3(a2, a, b, c); ins3(b2, a, b, c); ins3(c2, a, b, c);
    }
    __shared__ float sv[4][3];
    const int lane = tid & 63, wave = tid >> 6;
    if (lane == 0) { sv[wave][0] = a; sv[wave][1] = b; sv[wave][2] = c; }
    __syncthreads();
    if (tid == 0) {
        for (int w = 1; w < 4; ++w) {
            ins3(sv[w][0], a, b, c);
            ins3(sv[w][1], a, b, c);
            ins3(sv[w][2], a, b, c);
        }
        float* dst = cand + (size_t)row * 48 + chunk * 3;
        st_agent(&dst[0], a); st_agent(&dst[1], b); st_agent(&dst[2], c);
    }

    // ---- handoff 1: 16th-arriving block of this row finalizes the row ----
    // __syncthreads drains vmcnt for every wave -> tid0's sc1 stores are at
    // L3 before its rowcnt RMW can be observed (R5/R7-validated ordering).
    __shared__ bool amFin;
    __syncthreads();
    if (tid == 0) {
        const unsigned old = __hip_atomic_fetch_add(
            &rowcnt[row], 1u, __ATOMIC_RELAXED, __HIP_MEMORY_SCOPE_AGENT);
        amFin = (old == SPLIT - 1);
    }
    __syncthreads();                 // also fences: no load-hoist above RMW
    if (!amFin) return;              // block-uniform exit

    // ---- row finalize: wave 0 merges the row's 48 sc1-stored candidates ----
    {
        float pos = 0.0f; v4f rg = {0, 0, 0, 0};
        if (tid == 0) {              // independent loads, batched by compiler
            pos = posval[row];
            rg  = *reinterpret_cast<const v4f*>(&rowreg[row * CC]);
        }
        float ra = -FLT_MAX, rb = -FLT_MAX, rc = -FLT_MAX;
        if (tid < 48) ra = cand[(size_t)row * 48 + tid];  // coalesced round
        if (tid < 64) {
            for (int off = 32; off >= 1; off >>= 1) {
                const float a2 = __shfl_down(ra, off);
                const float b2 = __shfl_down(rb, off);
                const float c2 = __shfl_down(rc, off);
                ins3(a2, ra, rb, rc); ins3(b2, ra, rb, rc); ins3(c2, ra, rb, rc);
            }
        }
        if (tid == 0) {
            float loss = bce(pos, 1.0f)
                       + bce(ra, 0.0f) + bce(rb, 0.0f) + bce(rc, 0.0f);
            loss += rg.x + rg.y + rg.z + rg.w;   // smooth-L1 partials
            st_agent(&rowloss[row], loss);
        }
    }

    // ---- handoff 2: 128th row-finalizer reduces to the scalar ----
    __shared__ bool amLast;
    __syncthreads();                 // drains lane0's rowloss sc1 store
    if (tid == 0) {
        const unsigned d = __hip_atomic_fetch_add(
            done, 1u, __ATOMIC_RELAXED, __HIP_MEMORY_SCOPE_AGENT);
        amLast = (d == BB - 1);
    }
    __syncthreads();
    if (!amLast) return;             // block-uniform exit

    if (tid < 64) {
        float v = rowloss[tid] + rowloss[64 + tid];
        for (int off = 32; off >= 1; off >>= 1) v += __shfl_down(v, off);
        if (tid == 0) out[0] = v * (1.0f / (BB * CC));
    }
}

extern "C" void kernel_launch(void* const* d_in, const int* in_sizes, int n_in,
                              void* d_out, int out_size, void* d_ws, size_t ws_size,
                              hipStream_t stream) {
    const float* class_preds = (const float*)d_in[0];
    const float* reg_preds   = (const float*)d_in[1];
    const int*   box_idxs    = (const int*)d_in[2];
    const float* reg_targs   = (const float*)d_in[3];
    float* out = (float*)d_out;

    unsigned* rowcnt  = (unsigned*)d_ws;                    // 128 uints
    unsigned* done    = rowcnt + BB;                        // 1 uint (+3 pad)
    float*    cand    = (float*)(rowcnt + 132);             // 528 B in: 16B-aligned
    float*    posval  = cand + (size_t)BB * 48;             // 128 floats
    float*    rowreg  = posval + BB;                        // 512 floats
    float*    rowloss = rowreg + BB * CC;                   // 128 floats

    hipMemsetAsync(d_ws, 0, 528, stream);   // zero rowcnt+done (tiny fill node)
    k_fused<<<NBLK, 256, 0, stream>>>(class_preds, reg_preds, box_idxs,
                                      reg_targs, rowcnt, done, cand,
                                      posval, rowreg, rowloss, out);
}

// Round 12
// 16.207 us; speedup vs baseline: 1.6306x; 1.6306x over previous
//
#include <hip/hip_runtime.h>
#include <cfloat>

#define BB    128
#define CC    4
#define NBOXN 131072
#define SPLIT 8                  // chunk-blocks per row
#define NBLK  (BB * SPLIT)       // 1024 blocks = 4/CU exactly
#define F4_PER_CHUNK 4096        // 16384 elems / 4
#define F4_PER_STRIPE 16         // float4s per thread

typedef float v4f __attribute__((ext_vector_type(4)));

// sorted-insert into descending triple (a>=b>=c), 3 depth-1 ops via med3
__device__ __forceinline__ void ins3(float v, float& a, float& b, float& c) {
    const float na = fmaxf(a, v);
    const float nb = __builtin_amdgcn_fmed3f(a, b, v);
    const float nc = __builtin_amdgcn_fmed3f(b, c, v);
    a = na; b = nb; c = nc;
}

__device__ __forceinline__ float bce(float x, float t) {
    return fmaxf(x, 0.0f) - x * t + log1pf(expf(-fabsf(x)));
}

// ---- Kernel 1: exact per-chunk top-3 (anchor excluded), NT stream ----
__global__ __launch_bounds__(256) void k_chunk_top3(
        const float* __restrict__ cp,
        const float* __restrict__ rp,
        const int*   __restrict__ box_idxs,
        const float* __restrict__ rt,
        float*       __restrict__ cand,     // [BB*SPLIT*3]
        float*       __restrict__ posval,   // [BB]
        float*       __restrict__ rowreg) { // [BB*CC]
    const int row   = blockIdx.x >> 3;
    const int chunk = blockIdx.x & 7;
    const int tid   = threadIdx.x;
    const int bidx  = box_idxs[row];

    // side jobs hidden under the stream (one chunk-0 block per row)
    if (chunk == 0) {
        if (tid < CC) {
            const float pv = rp[((size_t)row * CC + tid) * NBOXN + bidx];
            const float d  = fabsf(pv - rt[row * CC + tid]);
            rowreg[row * CC + tid] = (d < 1.0f) ? 0.5f * d * d : (d - 0.5f);
        } else if (tid == CC) {
            posval[row] = cp[(size_t)row * NBOXN + bidx];
        }
    }

    const v4f* src = reinterpret_cast<const v4f*>(cp + (size_t)row * NBOXN)
                     + chunk * F4_PER_CHUNK;
    const int gbase = (chunk * F4_PER_CHUNK) << 2;

    // per-thread exact top-3; nontemporal read-once stream; 3 VALU/elem
    float a = -FLT_MAX, b = -FLT_MAX, c = -FLT_MAX;
    #pragma unroll
    for (int k = 0; k < F4_PER_STRIPE; ++k) {
        const int j = tid + (k << 8);
        v4f v = __builtin_nontemporal_load(&src[j]);
        const int g = gbase + (j << 2);
        if ((unsigned)(bidx - g) < 4u) {     // rare, exec-mask-skipped
            if      (bidx == g)     v.x = -FLT_MAX;
            else if (bidx == g + 1) v.y = -FLT_MAX;
            else if (bidx == g + 2) v.z = -FLT_MAX;
            else                    v.w = -FLT_MAX;
        }
        ins3(v.x, a, b, c); ins3(v.y, a, b, c);
        ins3(v.z, a, b, c); ins3(v.w, a, b, c);
    }

    // wave64 shuffle tree; lane 0's cone covers all 64 lanes exactly once
    for (int off = 32; off >= 1; off >>= 1) {
        const float a2 = __shfl_down(a, off);
        const float b2 = __shfl_down(b, off);
        const float c2 = __shfl_down(c, off);
        ins3(a2, a, b, c); ins3(b2, a, b, c); ins3(c2, a, b, c);
    }

    __shared__ float sv[4][3];
    const int lane = tid & 63, wave = tid >> 6;
    if (lane == 0) { sv[wave][0] = a; sv[wave][1] = b; sv[wave][2] = c; }
    __syncthreads();
    if (tid == 0) {
        for (int w = 1; w < 4; ++w) {
            ins3(sv[w][0], a, b, c);
            ins3(sv[w][1], a, b, c);
            ins3(sv[w][2], a, b, c);
        }
        float* dst = cand + (size_t)blockIdx.x * 3;
        dst[0] = a; dst[1] = b; dst[2] = c;
    }
}

// ---- Kernel 2: merge 24 exact candidates/row + loss + scalar reduce ----
__global__ __launch_bounds__(128) void k_final(
        const float* __restrict__ cand,
        const float* __restrict__ posval,
        const float* __restrict__ rowreg,
        float*       __restrict__ out) {
    const int r = threadIdx.x;   // one row per thread

    // batched loads: 6 x dwordx4 (cand row, 96 B) + 1 x dwordx4 + posval
    const v4f* pc = reinterpret_cast<const v4f*>(cand + (size_t)r * SPLIT * 3);
    v4f cv[6];
    #pragma unroll
    for (int q = 0; q < 6; ++q) cv[q] = pc[q];
    const v4f rg = reinterpret_cast<const v4f*>(rowreg)[r];
    const float pos = posval[r];

    float a = -FLT_MAX, b = -FLT_MAX, c = -FLT_MAX;
    #pragma unroll
    for (int q = 0; q < 6; ++q) {
        ins3(cv[q].x, a, b, c); ins3(cv[q].y, a, b, c);
        ins3(cv[q].z, a, b, c); ins3(cv[q].w, a, b, c);
    }

    float loss = bce(pos, 1.0f) + bce(a, 0.0f) + bce(b, 0.0f) + bce(c, 0.0f);
    loss += rg.x + rg.y + rg.z + rg.w;

    for (int off = 32; off >= 1; off >>= 1) loss += __shfl_down(loss, off);
    __shared__ float sm[2];
    if ((r & 63) == 0) sm[r >> 6] = loss;
    __syncthreads();
    if (r == 0) out[0] = (sm[0] + sm[1]) * (1.0f / (BB * CC));
}

extern "C" void kernel_launch(void* const* d_in, const int* in_sizes, int n_in,
                              void* d_out, int out_size, void* d_ws, size_t ws_size,
                              hipStream_t stream) {
    const float* class_preds = (const float*)d_in[0];
    const float* reg_preds   = (const float*)d_in[1];
    const int*   box_idxs    = (const int*)d_in[2];
    const float* reg_targs   = (const float*)d_in[3];
    float* out = (float*)d_out;

    float* cand   = (float*)d_ws;                   // NBLK*3 floats
    float* posval = cand + (size_t)NBLK * 3;        // BB floats
    float* rowreg = posval + BB;                    // BB*CC floats

    k_chunk_top3<<<NBLK, 256, 0, stream>>>(class_preds, reg_preds,
                                           box_idxs, reg_targs,
                                           cand, posval, rowreg);
    k_final<<<1, 128, 0, stream>>>(cand, posval, rowreg, out);
}